// Round 8
// baseline (143.633 us; speedup 1.0000x reference)
//
#include <hip/hip_runtime.h>
#include <hip/hip_bf16.h>

#define N_NODES 100000
#define N_EDGES 1600000
#define IN_DIM 256
#define OUT_DIM 128

typedef __attribute__((ext_vector_type(4))) float f32x4;
typedef __attribute__((ext_vector_type(8))) short s16x8;

__device__ inline unsigned short f2bf_us(float f) {
    union { __hip_bfloat16 h; unsigned short u; } v;
    v.h = __float2bfloat16(f);
    return v.u;
}

__device__ inline s16x8 pack8(const float4& a, const float4& b) {
    union { s16x8 v; __hip_bfloat162 h[4]; } u;
    u.h[0] = __float22bfloat162_rn(make_float2(a.x, a.y));
    u.h[1] = __float22bfloat162_rn(make_float2(a.z, a.w));
    u.h[2] = __float22bfloat162_rn(make_float2(b.x, b.y));
    u.h[3] = __float22bfloat162_rn(make_float2(b.z, b.w));
    return u.v;
}

// ---------------- WT = bf16(W^T) : [col][k], 128x256 ----------------
__global__ __launch_bounds__(256)
void wt_kernel(const float* __restrict__ W, unsigned short* __restrict__ WT) {
    const int t = blockIdx.x * 256 + threadIdx.x;   // 0..32767
    const int k = t >> 7;
    const int c = t & 127;
    WT[c * IN_DIM + k] = f2bf_us(W[t]);
}

// ---------------- GEMM: HWb(bf16 row-major) = bf16(H) @ bf16(W) --------------
// NO LDS (graph-replay corruption seen with 67KB LDS in R3).
// R7 fix: 16 rows/wave, 64 rows/block -> 1563 blocks (24 waves/CU), and the
// whole A row-slice issued upfront (16 outstanding float4 loads/lane) so HBM
// latency is hidden by MLP x occupancy, not just wave count.
__global__ __launch_bounds__(256, 4)
void gemm_mfma_kernel(const float* __restrict__ H,
                      const unsigned short* __restrict__ WT,
                      unsigned short* __restrict__ HWb) {
    const int tid  = threadIdx.x;
    const int wid  = tid >> 6;
    const int lane = tid & 63;
    const int lrow = lane & 15;
    const int kblk = lane >> 4;
    const int wrow = blockIdx.x * 64 + wid * 16;

    int r0 = wrow + lrow;  if (r0 >= N_NODES) r0 = N_NODES - 1;
    const float* p0 = H + (size_t)r0 * IN_DIM + kblk * 8;

    // Entire per-lane A slice: 8 K-steps x 8 floats = 16 float4, all in flight.
    float4 a[16];
    #pragma unroll
    for (int kc = 0; kc < 8; ++kc) {
        a[2 * kc]     = *(const float4*)(p0 + kc * 32);
        a[2 * kc + 1] = *(const float4*)(p0 + kc * 32 + 4);
    }

    f32x4 acc[8] = {};
    #pragma unroll
    for (int kc = 0; kc < 8; ++kc) {
        const s16x8 fa = pack8(a[2 * kc], a[2 * kc + 1]);
        const int kbase = kc * 32 + kblk * 8;
        #pragma unroll
        for (int n = 0; n < 8; ++n) {
            const s16x8 fb =
                *(const s16x8*)(WT + (size_t)(n * 16 + lrow) * IN_DIM + kbase);
            acc[n] = __builtin_amdgcn_mfma_f32_16x16x32_bf16(fa, fb, acc[n], 0, 0, 0);
        }
    }

    // D layout: col-within-tile = lane&15, row = (lane>>4)*4 + reg
    #pragma unroll
    for (int r = 0; r < 4; ++r) {
        const int grow = wrow + (lane >> 4) * 4 + r;
        if (grow < N_NODES) {
            #pragma unroll
            for (int n = 0; n < 8; ++n)
                HWb[(size_t)grow * OUT_DIM + n * 16 + (lane & 15)] =
                    f2bf_us(acc[n][r]);
        }
    }
}

// ---------------- row_ptr from sorted dst ----------------
__global__ __launch_bounds__(256)
void rowptr_kernel(const int* __restrict__ dst, int* __restrict__ row_ptr) {
    const int e = blockIdx.x * blockDim.x + threadIdx.x;
    if (e > N_EDGES) return;
    if (e == N_EDGES) {
        for (int n = dst[N_EDGES - 1] + 1; n <= N_NODES; ++n) row_ptr[n] = N_EDGES;
        return;
    }
    const int d = dst[e];
    const int dprev = (e == 0) ? -1 : dst[e - 1];
    for (int n = dprev + 1; n <= d; ++n) row_ptr[n] = e;
}

// ---------------- SpMM v3: out = A @ HW(bf16) + bias ----------------
// Wave = 1 node. eslot = lane>>4 (4 edges per gather instr), cg = lane&15
// (16 B of the 256 B row per lane). Unroll x2 -> 8 edges in flight.
// shfl_xor(16,32) reduce; lanes 0..15 store the fp32 row. Deterministic.
__global__ __launch_bounds__(256)
void spmm_v3_kernel(const uint4* __restrict__ HWq, const float* __restrict__ vals,
                    const int* __restrict__ src, const int* __restrict__ row_ptr,
                    const float* __restrict__ bias, float* __restrict__ out) {
    const int node = blockIdx.x * 4 + (threadIdx.x >> 6);
    if (node >= N_NODES) return;
    const int lane  = threadIdx.x & 63;
    const int eslot = lane >> 4;   // 0..3
    const int cg    = lane & 15;   // uint4 (16B) index within 256B row

    const int lo = row_ptr[node];
    const int hi = row_ptr[node + 1];

    float acc[8] = {};
    for (int base = lo; base < hi; base += 8) {
        const int e0 = base + eslot;
        const int e1 = base + 4 + eslot;
        const bool m0 = e0 < hi;
        const bool m1 = e1 < hi;
        const int ec0 = m0 ? e0 : lo;
        const int ec1 = m1 ? e1 : lo;
        const int   s0 = src[ec0];
        const int   s1 = src[ec1];
        const float v0 = m0 ? vals[ec0] : 0.f;
        const float v1 = m1 ? vals[ec1] : 0.f;
        const uint4 g0 = HWq[(size_t)s0 * 16 + cg];
        const uint4 g1 = HWq[(size_t)s1 * 16 + cg];

        const unsigned* u0 = (const unsigned*)&g0;
        const unsigned* u1 = (const unsigned*)&g1;
        #pragma unroll
        for (int j = 0; j < 4; ++j) {
            acc[2*j]   = fmaf(__uint_as_float(u0[j] << 16),         v0, acc[2*j]);
            acc[2*j+1] = fmaf(__uint_as_float(u0[j] & 0xffff0000u), v0, acc[2*j+1]);
        }
        #pragma unroll
        for (int j = 0; j < 4; ++j) {
            acc[2*j]   = fmaf(__uint_as_float(u1[j] << 16),         v1, acc[2*j]);
            acc[2*j+1] = fmaf(__uint_as_float(u1[j] & 0xffff0000u), v1, acc[2*j+1]);
        }
    }

    #pragma unroll
    for (int i = 0; i < 8; ++i) {
        acc[i] += __shfl_xor(acc[i], 16);
        acc[i] += __shfl_xor(acc[i], 32);
    }

    if (lane < 16) {
        float4 o0, o1;
        const float* bb = bias + cg * 8;
        o0.x = acc[0] + bb[0]; o0.y = acc[1] + bb[1];
        o0.z = acc[2] + bb[2]; o0.w = acc[3] + bb[3];
        o1.x = acc[4] + bb[4]; o1.y = acc[5] + bb[5];
        o1.z = acc[6] + bb[6]; o1.w = acc[7] + bb[7];
        float* p = out + (size_t)node * OUT_DIM + cg * 8;
        *(float4*)(p)     = o0;
        *(float4*)(p + 4) = o1;
    }
}

extern "C" void kernel_launch(void* const* d_in, const int* in_sizes, int n_in,
                              void* d_out, int out_size, void* d_ws, size_t ws_size,
                              hipStream_t stream) {
    const float* H    = (const float*)d_in[0];
    const float* W    = (const float*)d_in[1];
    const float* bias = (const float*)d_in[2];
    const float* vals = (const float*)d_in[3];
    const int*   src  = (const int*)d_in[4];
    const int*   dst  = (const int*)d_in[5];
    float* out = (float*)d_out;

    unsigned short* HWb = (unsigned short*)d_ws;   // 25.6 MB bf16 row-major
    const size_t hw_bytes = (size_t)N_NODES * OUT_DIM * sizeof(unsigned short);
    int* row_ptr = (int*)((char*)d_ws + hw_bytes);
    size_t wt_off = hw_bytes + (size_t)(N_NODES + 1) * sizeof(int);
    wt_off = (wt_off + 127) & ~(size_t)127;
    unsigned short* WT = (unsigned short*)((char*)d_ws + wt_off);

    wt_kernel<<<dim3((IN_DIM * OUT_DIM) / 256), dim3(256), 0, stream>>>(W, WT);
    rowptr_kernel<<<dim3((N_EDGES + 256) / 256), dim3(256), 0, stream>>>(dst, row_ptr);
    gemm_mfma_kernel<<<dim3((N_NODES + 63) / 64), dim3(256), 0, stream>>>(H, WT, HWb);
    spmm_v3_kernel<<<dim3((N_NODES + 3) / 4), dim3(256), 0, stream>>>(
        (const uint4*)HWb, vals, src, row_ptr, bias, out);
}

// Round 9
// 121.153 us; speedup vs baseline: 1.1856x; 1.1856x over previous
//
#include <hip/hip_runtime.h>
#include <hip/hip_bf16.h>

#define N_NODES 100000
#define N_EDGES 1600000
#define IN_DIM 256
#define OUT_DIM 128

typedef __attribute__((ext_vector_type(4))) float f32x4;
typedef __attribute__((ext_vector_type(8))) short s16x8;

__device__ inline unsigned short f2bf_us(float f) {
    union { __hip_bfloat16 h; unsigned short u; } v;
    v.h = __float2bfloat16(f);
    return v.u;
}

__device__ inline s16x8 pack8(const float4& a, const float4& b) {
    union { s16x8 v; __hip_bfloat162 h[4]; } u;
    u.h[0] = __float22bfloat162_rn(make_float2(a.x, a.y));
    u.h[1] = __float22bfloat162_rn(make_float2(a.z, a.w));
    u.h[2] = __float22bfloat162_rn(make_float2(b.x, b.y));
    u.h[3] = __float22bfloat162_rn(make_float2(b.z, b.w));
    return u.v;
}

// ------- WTx: wave-order permuted bf16 weights -------------------------------
// WTx[n][kc][kblk][lrow][j] = W[kc*32 + kblk*8 + j][n*16 + lrow]
// so one (n,kc) B-fragment load is 64 lanes x 16B = 1KB CONTIGUOUS.
__global__ __launch_bounds__(256)
void wt_kernel(const float* __restrict__ W, unsigned short* __restrict__ WTx) {
    const int t = blockIdx.x * 256 + threadIdx.x;   // 0..32767, dest-linear
    const int j    = t & 7;
    const int lrow = (t >> 3) & 15;
    const int kblk = (t >> 7) & 3;
    const int kc   = (t >> 9) & 7;
    const int n    = t >> 12;
    const int k    = kc * 32 + kblk * 8 + j;
    const int c    = n * 16 + lrow;
    WTx[t] = f2bf_us(W[(size_t)k * OUT_DIM + c]);
}

// ---------------- GEMM: HWb(bf16 row-major) = bf16(H) @ bf16(W) --------------
// NO LDS (graph-replay corruption seen with 67KB LDS in R3). R7 structure
// (32 rows/wave, 128 rows/block) + R8 fix: contiguous B-fragment loads from
// the permuted WTx (1KB/instr instead of 16 scattered rows).
__global__ __launch_bounds__(256, 2)
void gemm_mfma_kernel(const float* __restrict__ H,
                      const unsigned short* __restrict__ WTx,
                      unsigned short* __restrict__ HWb) {
    const int tid  = threadIdx.x;
    const int wid  = tid >> 6;
    const int lane = tid & 63;
    const int lrow = lane & 15;
    const int kblk = lane >> 4;
    const int wrow = blockIdx.x * 128 + wid * 32;

    int r0 = wrow + lrow;       if (r0 >= N_NODES) r0 = N_NODES - 1;
    int r1 = wrow + lrow + 16;  if (r1 >= N_NODES) r1 = N_NODES - 1;
    const float* p0 = H + (size_t)r0 * IN_DIM + kblk * 8;
    const float* p1 = H + (size_t)r1 * IN_DIM + kblk * 8;

    // per-lane base into WTx for this lane's fragment slot
    const unsigned short* wbase = WTx + (size_t)(kblk * 16 + lrow) * 8;

    f32x4 acc[2][8] = {};

    float4 c00 = *(const float4*)(p0);
    float4 c01 = *(const float4*)(p0 + 4);
    float4 c10 = *(const float4*)(p1);
    float4 c11 = *(const float4*)(p1 + 4);

    #pragma unroll
    for (int kc = 0; kc < 8; ++kc) {
        const s16x8 fa0 = pack8(c00, c01);
        const s16x8 fa1 = pack8(c10, c11);
        if (kc < 7) {
            const float* q0 = p0 + (kc + 1) * 32;
            const float* q1 = p1 + (kc + 1) * 32;
            c00 = *(const float4*)(q0);
            c01 = *(const float4*)(q0 + 4);
            c10 = *(const float4*)(q1);
            c11 = *(const float4*)(q1 + 4);
        }
        #pragma unroll
        for (int n = 0; n < 8; ++n) {
            // WTx[n][kc][kblk][lrow][0..7]
            const s16x8 fb = *(const s16x8*)(wbase + ((size_t)(n * 8 + kc) << 9));
            acc[0][n] = __builtin_amdgcn_mfma_f32_16x16x32_bf16(fa0, fb, acc[0][n], 0, 0, 0);
            acc[1][n] = __builtin_amdgcn_mfma_f32_16x16x32_bf16(fa1, fb, acc[1][n], 0, 0, 0);
        }
    }

    // D layout: col-within-tile = lane&15, row = (lane>>4)*4 + reg
    #pragma unroll
    for (int mt = 0; mt < 2; ++mt) {
        #pragma unroll
        for (int r = 0; r < 4; ++r) {
            const int grow = wrow + mt * 16 + (lane >> 4) * 4 + r;
            if (grow < N_NODES) {
                #pragma unroll
                for (int n = 0; n < 8; ++n)
                    HWb[(size_t)grow * OUT_DIM + n * 16 + (lane & 15)] =
                        f2bf_us(acc[mt][n][r]);
            }
        }
    }
}

// ---------------- row_ptr from sorted dst ----------------
__global__ __launch_bounds__(256)
void rowptr_kernel(const int* __restrict__ dst, int* __restrict__ row_ptr) {
    const int e = blockIdx.x * blockDim.x + threadIdx.x;
    if (e > N_EDGES) return;
    if (e == N_EDGES) {
        for (int n = dst[N_EDGES - 1] + 1; n <= N_NODES; ++n) row_ptr[n] = N_EDGES;
        return;
    }
    const int d = dst[e];
    const int dprev = (e == 0) ? -1 : dst[e - 1];
    for (int n = dprev + 1; n <= d; ++n) row_ptr[n] = e;
}

// ---------------- SpMM v3: out = A @ HW(bf16) + bias ----------------
// Wave = 1 node. eslot = lane>>4 (4 edges per gather instr), cg = lane&15
// (16 B of the 256 B row per lane). Unroll x2 -> 8 edges in flight.
// shfl_xor(16,32) reduce; lanes 0..15 store the fp32 row. Deterministic.
__global__ __launch_bounds__(256)
void spmm_v3_kernel(const uint4* __restrict__ HWq, const float* __restrict__ vals,
                    const int* __restrict__ src, const int* __restrict__ row_ptr,
                    const float* __restrict__ bias, float* __restrict__ out) {
    const int node = blockIdx.x * 4 + (threadIdx.x >> 6);
    if (node >= N_NODES) return;
    const int lane  = threadIdx.x & 63;
    const int eslot = lane >> 4;   // 0..3
    const int cg    = lane & 15;   // uint4 (16B) index within 256B row

    const int lo = row_ptr[node];
    const int hi = row_ptr[node + 1];

    float acc[8] = {};
    for (int base = lo; base < hi; base += 8) {
        const int e0 = base + eslot;
        const int e1 = base + 4 + eslot;
        const bool m0 = e0 < hi;
        const bool m1 = e1 < hi;
        const int ec0 = m0 ? e0 : lo;
        const int ec1 = m1 ? e1 : lo;
        const int   s0 = src[ec0];
        const int   s1 = src[ec1];
        const float v0 = m0 ? vals[ec0] : 0.f;
        const float v1 = m1 ? vals[ec1] : 0.f;
        const uint4 g0 = HWq[(size_t)s0 * 16 + cg];
        const uint4 g1 = HWq[(size_t)s1 * 16 + cg];

        const unsigned* u0 = (const unsigned*)&g0;
        const unsigned* u1 = (const unsigned*)&g1;
        #pragma unroll
        for (int j = 0; j < 4; ++j) {
            acc[2*j]   = fmaf(__uint_as_float(u0[j] << 16),         v0, acc[2*j]);
            acc[2*j+1] = fmaf(__uint_as_float(u0[j] & 0xffff0000u), v0, acc[2*j+1]);
        }
        #pragma unroll
        for (int j = 0; j < 4; ++j) {
            acc[2*j]   = fmaf(__uint_as_float(u1[j] << 16),         v1, acc[2*j]);
            acc[2*j+1] = fmaf(__uint_as_float(u1[j] & 0xffff0000u), v1, acc[2*j+1]);
        }
    }

    #pragma unroll
    for (int i = 0; i < 8; ++i) {
        acc[i] += __shfl_xor(acc[i], 16);
        acc[i] += __shfl_xor(acc[i], 32);
    }

    if (lane < 16) {
        float4 o0, o1;
        const float* bb = bias + cg * 8;
        o0.x = acc[0] + bb[0]; o0.y = acc[1] + bb[1];
        o0.z = acc[2] + bb[2]; o0.w = acc[3] + bb[3];
        o1.x = acc[4] + bb[4]; o1.y = acc[5] + bb[5];
        o1.z = acc[6] + bb[6]; o1.w = acc[7] + bb[7];
        float* p = out + (size_t)node * OUT_DIM + cg * 8;
        *(float4*)(p)     = o0;
        *(float4*)(p + 4) = o1;
    }
}

extern "C" void kernel_launch(void* const* d_in, const int* in_sizes, int n_in,
                              void* d_out, int out_size, void* d_ws, size_t ws_size,
                              hipStream_t stream) {
    const float* H    = (const float*)d_in[0];
    const float* W    = (const float*)d_in[1];
    const float* bias = (const float*)d_in[2];
    const float* vals = (const float*)d_in[3];
    const int*   src  = (const int*)d_in[4];
    const int*   dst  = (const int*)d_in[5];
    float* out = (float*)d_out;

    unsigned short* HWb = (unsigned short*)d_ws;   // 25.6 MB bf16 row-major
    const size_t hw_bytes = (size_t)N_NODES * OUT_DIM * sizeof(unsigned short);
    int* row_ptr = (int*)((char*)d_ws + hw_bytes);
    size_t wt_off = hw_bytes + (size_t)(N_NODES + 1) * sizeof(int);
    wt_off = (wt_off + 127) & ~(size_t)127;
    unsigned short* WTx = (unsigned short*)((char*)d_ws + wt_off);

    wt_kernel<<<dim3((IN_DIM * OUT_DIM) / 256), dim3(256), 0, stream>>>(W, WTx);
    rowptr_kernel<<<dim3((N_EDGES + 256) / 256), dim3(256), 0, stream>>>(dst, row_ptr);
    gemm_mfma_kernel<<<dim3((N_NODES + 127) / 128), dim3(256), 0, stream>>>(H, WTx, HWb);
    spmm_v3_kernel<<<dim3((N_NODES + 3) / 4), dim3(256), 0, stream>>>(
        (const uint4*)HWb, vals, src, row_ptr, bias, out);
}

// Round 10
// 105.384 us; speedup vs baseline: 1.3630x; 1.1496x over previous
//
#include <hip/hip_runtime.h>
#include <hip/hip_bf16.h>

#define N_NODES 100000
#define N_EDGES 1600000
#define IN_DIM 256
#define OUT_DIM 128

typedef __attribute__((ext_vector_type(4))) float f32x4;
typedef __attribute__((ext_vector_type(8))) short s16x8;

__device__ inline unsigned short f2bf_us(float f) {
    union { __hip_bfloat16 h; unsigned short u; } v;
    v.h = __float2bfloat16(f);
    return v.u;
}

__device__ inline s16x8 pack8(const float4& a, const float4& b) {
    union { s16x8 v; __hip_bfloat162 h[4]; } u;
    u.h[0] = __float22bfloat162_rn(make_float2(a.x, a.y));
    u.h[1] = __float22bfloat162_rn(make_float2(a.z, a.w));
    u.h[2] = __float22bfloat162_rn(make_float2(b.x, b.y));
    u.h[3] = __float22bfloat162_rn(make_float2(b.z, b.w));
    return u.v;
}

// async global->LDS, 16B per lane; lds dest = wave-uniform base + lane*16
__device__ inline void gload_lds16(const float* g, float* l) {
    __builtin_amdgcn_global_load_lds(
        (const __attribute__((address_space(1))) unsigned*)g,
        (__attribute__((address_space(3))) unsigned*)l, 16, 0, 0);
}

// ------- WTx: wave-order permuted bf16 weights (as R9) -----------------------
// WTx[n][kc][kblk][lrow][j] = W[kc*32 + kblk*8 + j][n*16 + lrow]
__global__ __launch_bounds__(256)
void wt_kernel(const float* __restrict__ W, unsigned short* __restrict__ WTx) {
    const int t = blockIdx.x * 256 + threadIdx.x;   // 0..32767, dest-linear
    const int j    = t & 7;
    const int lrow = (t >> 3) & 15;
    const int kblk = (t >> 7) & 3;
    const int kc   = (t >> 9) & 7;
    const int n    = t >> 12;
    const int k    = kc * 32 + kblk * 8 + j;
    const int c    = n * 16 + lrow;
    WTx[t] = f2bf_us(W[(size_t)k * OUT_DIM + c]);
}

// ---------------- GEMM: HWp = bf16(H) @ bf16(W), LDS-staged ------------------
// 128 rows/block, 4 waves (32 rows each). H staged fp32 into 2x16KB LDS via
// global_load_lds (async, no VGPR round-trip), 16B-unit XOR swizzle applied on
// the GLOBAL source (LDS dest stays linear, m173). One barrier per K-step.
// C-write: permuted row layout HWp[row][c*8+n] -> 8x16B contiguous stores.
__global__ __launch_bounds__(256, 3)
void gemm_mfma_kernel(const float* __restrict__ H,
                      const unsigned short* __restrict__ WTx,
                      unsigned short* __restrict__ HWp) {
    __shared__ float Hs[2][4096];   // 2 x 16KB = 1024 16B-units per buffer

    const int tid  = threadIdx.x;
    const int wid  = tid >> 6;
    const int lane = tid & 63;
    const int lrow = lane & 15;
    const int kblk = lane >> 4;
    const int brow = blockIdx.x * 128;

    const unsigned short* wbase = WTx + (size_t)(kblk * 16 + lrow) * 8;

    f32x4 acc[2][8] = {};

    // stage K-step kc into buffer b: 4 instrs/thread, 16KB total.
    // physical unit idx = linear; logical float4-idx = phys ^ (row&7).
    auto stage = [&](int b, int kc) {
        #pragma unroll
        for (int i = 0; i < 4; ++i) {
            const int ubase = i * 256 + wid * 64;     // wave-uniform unit base
            const int unit  = ubase + lane;
            const int row   = unit >> 3;
            const int ul    = (unit & 7) ^ (row & 7); // swizzled source unit
            int grow = brow + row; if (grow >= N_NODES) grow = N_NODES - 1;
            const float* gsrc = H + (size_t)grow * IN_DIM + kc * 32 + ul * 4;
            gload_lds16(gsrc, &Hs[b][ubase * 4]);
        }
    };

    stage(0, 0);
    __syncthreads();

    for (int kc = 0; kc < 8; ++kc) {
        const int cur = kc & 1;
        if (kc < 7) stage(cur ^ 1, kc + 1);

        s16x8 fa[2];
        #pragma unroll
        for (int mt = 0; mt < 2; ++mt) {
            const int row = wid * 32 + mt * 16 + lrow;
            const int u0  = (kblk * 2) ^ (row & 7);
            const int u1  = (kblk * 2 + 1) ^ (row & 7);
            const float4 x0 = *(const float4*)&Hs[cur][(row * 8 + u0) * 4];
            const float4 x1 = *(const float4*)&Hs[cur][(row * 8 + u1) * 4];
            fa[mt] = pack8(x0, x1);
        }
        #pragma unroll
        for (int n = 0; n < 8; ++n) {
            const s16x8 fb = *(const s16x8*)(wbase + ((size_t)(n * 8 + kc) << 9));
            acc[0][n] = __builtin_amdgcn_mfma_f32_16x16x32_bf16(fa[0], fb, acc[0][n], 0, 0, 0);
            acc[1][n] = __builtin_amdgcn_mfma_f32_16x16x32_bf16(fa[1], fb, acc[1][n], 0, 0, 0);
        }
        __syncthreads();
    }

    // C-write, permuted: HWp[grow][ (lane&15)*8 + n ], 16B contiguous/thread.
    const int c = lane & 15;
    #pragma unroll
    for (int mt = 0; mt < 2; ++mt) {
        #pragma unroll
        for (int r = 0; r < 4; ++r) {
            const int grow = brow + wid * 32 + mt * 16 + (lane >> 4) * 4 + r;
            if (grow < N_NODES) {
                unsigned short tmp[8];
                #pragma unroll
                for (int n = 0; n < 8; ++n) tmp[n] = f2bf_us(acc[mt][n][r]);
                *(s16x8*)(HWp + (size_t)grow * OUT_DIM + c * 8) = *(const s16x8*)tmp;
            }
        }
    }
}

// ---------------- row_ptr from sorted dst ----------------
__global__ __launch_bounds__(256)
void rowptr_kernel(const int* __restrict__ dst, int* __restrict__ row_ptr) {
    const int e = blockIdx.x * blockDim.x + threadIdx.x;
    if (e > N_EDGES) return;
    if (e == N_EDGES) {
        for (int n = dst[N_EDGES - 1] + 1; n <= N_NODES; ++n) row_ptr[n] = N_EDGES;
        return;
    }
    const int d = dst[e];
    const int dprev = (e == 0) ? -1 : dst[e - 1];
    for (int n = dprev + 1; n <= d; ++n) row_ptr[n] = e;
}

// ---------------- SpMM: out = A @ HWp + bias ----------------
// Inner loop identical to R7-R9 (proven ~50us). Epilogue remapped for the
// permuted HWp row layout: acc[j] corresponds to true column j*16 + cg.
__global__ __launch_bounds__(256)
void spmm_v3_kernel(const uint4* __restrict__ HWq, const float* __restrict__ vals,
                    const int* __restrict__ src, const int* __restrict__ row_ptr,
                    const float* __restrict__ bias, float* __restrict__ out) {
    const int node = blockIdx.x * 4 + (threadIdx.x >> 6);
    if (node >= N_NODES) return;
    const int lane  = threadIdx.x & 63;
    const int eslot = lane >> 4;   // 0..3
    const int cg    = lane & 15;   // 16B chunk within 256B row

    const int lo = row_ptr[node];
    const int hi = row_ptr[node + 1];

    float acc[8] = {};
    for (int base = lo; base < hi; base += 8) {
        const int e0 = base + eslot;
        const int e1 = base + 4 + eslot;
        const bool m0 = e0 < hi;
        const bool m1 = e1 < hi;
        const int ec0 = m0 ? e0 : lo;
        const int ec1 = m1 ? e1 : lo;
        const int   s0 = src[ec0];
        const int   s1 = src[ec1];
        const float v0 = m0 ? vals[ec0] : 0.f;
        const float v1 = m1 ? vals[ec1] : 0.f;
        const uint4 g0 = HWq[(size_t)s0 * 16 + cg];
        const uint4 g1 = HWq[(size_t)s1 * 16 + cg];

        const unsigned* u0 = (const unsigned*)&g0;
        const unsigned* u1 = (const unsigned*)&g1;
        #pragma unroll
        for (int j = 0; j < 4; ++j) {
            acc[2*j]   = fmaf(__uint_as_float(u0[j] << 16),         v0, acc[2*j]);
            acc[2*j+1] = fmaf(__uint_as_float(u0[j] & 0xffff0000u), v0, acc[2*j+1]);
        }
        #pragma unroll
        for (int j = 0; j < 4; ++j) {
            acc[2*j]   = fmaf(__uint_as_float(u1[j] << 16),         v1, acc[2*j]);
            acc[2*j+1] = fmaf(__uint_as_float(u1[j] & 0xffff0000u), v1, acc[2*j+1]);
        }
    }

    #pragma unroll
    for (int i = 0; i < 8; ++i) {
        acc[i] += __shfl_xor(acc[i], 16);
        acc[i] += __shfl_xor(acc[i], 32);
    }

    if (lane < 16) {
        #pragma unroll
        for (int j = 0; j < 8; ++j)
            out[(size_t)node * OUT_DIM + j * 16 + cg] = acc[j] + bias[j * 16 + cg];
    }
}

extern "C" void kernel_launch(void* const* d_in, const int* in_sizes, int n_in,
                              void* d_out, int out_size, void* d_ws, size_t ws_size,
                              hipStream_t stream) {
    const float* H    = (const float*)d_in[0];
    const float* W    = (const float*)d_in[1];
    const float* bias = (const float*)d_in[2];
    const float* vals = (const float*)d_in[3];
    const int*   src  = (const int*)d_in[4];
    const int*   dst  = (const int*)d_in[5];
    float* out = (float*)d_out;

    unsigned short* HWp = (unsigned short*)d_ws;   // 25.6 MB bf16, permuted rows
    const size_t hw_bytes = (size_t)N_NODES * OUT_DIM * sizeof(unsigned short);
    int* row_ptr = (int*)((char*)d_ws + hw_bytes);
    size_t wt_off = hw_bytes + (size_t)(N_NODES + 1) * sizeof(int);
    wt_off = (wt_off + 127) & ~(size_t)127;
    unsigned short* WTx = (unsigned short*)((char*)d_ws + wt_off);

    wt_kernel<<<dim3((IN_DIM * OUT_DIM) / 256), dim3(256), 0, stream>>>(W, WTx);
    rowptr_kernel<<<dim3((N_EDGES + 256) / 256), dim3(256), 0, stream>>>(dst, row_ptr);
    gemm_mfma_kernel<<<dim3((N_NODES + 127) / 128), dim3(256), 0, stream>>>(H, WTx, HWp);
    spmm_v3_kernel<<<dim3((N_NODES + 3) / 4), dim3(256), 0, stream>>>(
        (const uint4*)HWp, vals, src, row_ptr, bias, out);
}

// Round 11
// 102.992 us; speedup vs baseline: 1.3946x; 1.0232x over previous
//
#include <hip/hip_runtime.h>
#include <hip/hip_bf16.h>

#define N_NODES 100000
#define N_EDGES 1600000
#define IN_DIM 256
#define OUT_DIM 128

typedef __attribute__((ext_vector_type(4))) float f32x4;
typedef __attribute__((ext_vector_type(8))) short s16x8;

__device__ inline unsigned short f2bf_us(float f) {
    union { __hip_bfloat16 h; unsigned short u; } v;
    v.h = __float2bfloat16(f);
    return v.u;
}

__device__ inline s16x8 pack8(const float4& a, const float4& b) {
    union { s16x8 v; __hip_bfloat162 h[4]; } u;
    u.h[0] = __float22bfloat162_rn(make_float2(a.x, a.y));
    u.h[1] = __float22bfloat162_rn(make_float2(a.z, a.w));
    u.h[2] = __float22bfloat162_rn(make_float2(b.x, b.y));
    u.h[3] = __float22bfloat162_rn(make_float2(b.z, b.w));
    return u.v;
}

// async global->LDS, 16B per lane; lds dest = wave-uniform base + lane*16
__device__ inline void gload_lds16(const float* g, float* l) {
    __builtin_amdgcn_global_load_lds(
        (const __attribute__((address_space(1))) unsigned*)g,
        (__attribute__((address_space(3))) unsigned*)l, 16, 0, 0);
}

// ------- WTx: wave-order permuted bf16 weights -------------------------------
// WTx[n][kc][kblk][lrow][j] = W[kc*32 + kblk*8 + j][n*16 + lrow]
__global__ __launch_bounds__(256)
void wt_kernel(const float* __restrict__ W, unsigned short* __restrict__ WTx) {
    const int t = blockIdx.x * 256 + threadIdx.x;   // 0..32767, dest-linear
    const int j    = t & 7;
    const int lrow = (t >> 3) & 15;
    const int kblk = (t >> 7) & 3;
    const int kc   = (t >> 9) & 7;
    const int n    = t >> 12;
    const int k    = kc * 32 + kblk * 8 + j;
    const int c    = n * 16 + lrow;
    WTx[t] = f2bf_us(W[(size_t)k * OUT_DIM + c]);
}

// ---------------- GEMM: HWp = bf16(H) @ bf16(W), LDS-staged (R10, ~28us) -----
__global__ __launch_bounds__(256, 3)
void gemm_mfma_kernel(const float* __restrict__ H,
                      const unsigned short* __restrict__ WTx,
                      unsigned short* __restrict__ HWp) {
    __shared__ float Hs[2][4096];   // 2 x 16KB = 1024 16B-units per buffer

    const int tid  = threadIdx.x;
    const int wid  = tid >> 6;
    const int lane = tid & 63;
    const int lrow = lane & 15;
    const int kblk = lane >> 4;
    const int brow = blockIdx.x * 128;

    const unsigned short* wbase = WTx + (size_t)(kblk * 16 + lrow) * 8;

    f32x4 acc[2][8] = {};

    auto stage = [&](int b, int kc) {
        #pragma unroll
        for (int i = 0; i < 4; ++i) {
            const int ubase = i * 256 + wid * 64;     // wave-uniform unit base
            const int unit  = ubase + lane;
            const int row   = unit >> 3;
            const int ul    = (unit & 7) ^ (row & 7); // swizzled source unit
            int grow = brow + row; if (grow >= N_NODES) grow = N_NODES - 1;
            const float* gsrc = H + (size_t)grow * IN_DIM + kc * 32 + ul * 4;
            gload_lds16(gsrc, &Hs[b][ubase * 4]);
        }
    };

    stage(0, 0);
    __syncthreads();

    for (int kc = 0; kc < 8; ++kc) {
        const int cur = kc & 1;
        if (kc < 7) stage(cur ^ 1, kc + 1);

        s16x8 fa[2];
        #pragma unroll
        for (int mt = 0; mt < 2; ++mt) {
            const int row = wid * 32 + mt * 16 + lrow;
            const int u0  = (kblk * 2) ^ (row & 7);
            const int u1  = (kblk * 2 + 1) ^ (row & 7);
            const float4 x0 = *(const float4*)&Hs[cur][(row * 8 + u0) * 4];
            const float4 x1 = *(const float4*)&Hs[cur][(row * 8 + u1) * 4];
            fa[mt] = pack8(x0, x1);
        }
        #pragma unroll
        for (int n = 0; n < 8; ++n) {
            const s16x8 fb = *(const s16x8*)(wbase + ((size_t)(n * 8 + kc) << 9));
            acc[0][n] = __builtin_amdgcn_mfma_f32_16x16x32_bf16(fa[0], fb, acc[0][n], 0, 0, 0);
            acc[1][n] = __builtin_amdgcn_mfma_f32_16x16x32_bf16(fa[1], fb, acc[1][n], 0, 0, 0);
        }
        __syncthreads();
    }

    const int c = lane & 15;
    #pragma unroll
    for (int mt = 0; mt < 2; ++mt) {
        #pragma unroll
        for (int r = 0; r < 4; ++r) {
            const int grow = brow + wid * 32 + mt * 16 + (lane >> 4) * 4 + r;
            if (grow < N_NODES) {
                unsigned short tmp[8];
                #pragma unroll
                for (int n = 0; n < 8; ++n) tmp[n] = f2bf_us(acc[mt][n][r]);
                *(s16x8*)(HWp + (size_t)grow * OUT_DIM + c * 8) = *(const s16x8*)tmp;
            }
        }
    }
}

// ---------------- row_ptr from sorted dst ----------------
__global__ __launch_bounds__(256)
void rowptr_kernel(const int* __restrict__ dst, int* __restrict__ row_ptr) {
    const int e = blockIdx.x * blockDim.x + threadIdx.x;
    if (e > N_EDGES) return;
    if (e == N_EDGES) {
        for (int n = dst[N_EDGES - 1] + 1; n <= N_NODES; ++n) row_ptr[n] = N_EDGES;
        return;
    }
    const int d = dst[e];
    const int dprev = (e == 0) ? -1 : dst[e - 1];
    for (int n = dprev + 1; n <= d; ++n) row_ptr[n] = e;
}

// ---------------- SpMM v4: out = A @ HWp + bias ----------------
// Wave = 1 node; eslot = lane>>4 (4 edges/instr), cg = lane&15 (16B of row).
// R10 fix: unroll x4 -> 16 edges per iteration, 4 uint4 gathers in flight
// (typical node, deg~16, completes in ONE iteration). Deterministic.
__global__ __launch_bounds__(256)
void spmm_v4_kernel(const uint4* __restrict__ HWq, const float* __restrict__ vals,
                    const int* __restrict__ src, const int* __restrict__ row_ptr,
                    const float* __restrict__ bias, float* __restrict__ out) {
    const int node = blockIdx.x * 4 + (threadIdx.x >> 6);
    if (node >= N_NODES) return;
    const int lane  = threadIdx.x & 63;
    const int eslot = lane >> 4;   // 0..3
    const int cg    = lane & 15;   // 16B chunk within 256B row

    const int lo = row_ptr[node];
    const int hi = row_ptr[node + 1];

    float acc[8] = {};
    for (int base = lo; base < hi; base += 16) {
        int ec[4]; float v[4];
        #pragma unroll
        for (int j = 0; j < 4; ++j) {
            const int e = base + 4 * j + eslot;
            const bool m = e < hi;
            ec[j] = m ? e : lo;
            v[j]  = m ? vals[ec[j]] : 0.f;
        }
        int s[4];
        #pragma unroll
        for (int j = 0; j < 4; ++j) s[j] = src[ec[j]];
        uint4 g[4];
        #pragma unroll
        for (int j = 0; j < 4; ++j) g[j] = HWq[(size_t)s[j] * 16 + cg];

        #pragma unroll
        for (int j = 0; j < 4; ++j) {
            const unsigned* u = (const unsigned*)&g[j];
            #pragma unroll
            for (int q = 0; q < 4; ++q) {
                acc[2*q]   = fmaf(__uint_as_float(u[q] << 16),         v[j], acc[2*q]);
                acc[2*q+1] = fmaf(__uint_as_float(u[q] & 0xffff0000u), v[j], acc[2*q+1]);
            }
        }
    }

    #pragma unroll
    for (int i = 0; i < 8; ++i) {
        acc[i] += __shfl_xor(acc[i], 16);
        acc[i] += __shfl_xor(acc[i], 32);
    }

    if (lane < 16) {
        #pragma unroll
        for (int j = 0; j < 8; ++j)
            out[(size_t)node * OUT_DIM + j * 16 + cg] = acc[j] + bias[j * 16 + cg];
    }
}

extern "C" void kernel_launch(void* const* d_in, const int* in_sizes, int n_in,
                              void* d_out, int out_size, void* d_ws, size_t ws_size,
                              hipStream_t stream) {
    const float* H    = (const float*)d_in[0];
    const float* W    = (const float*)d_in[1];
    const float* bias = (const float*)d_in[2];
    const float* vals = (const float*)d_in[3];
    const int*   src  = (const int*)d_in[4];
    const int*   dst  = (const int*)d_in[5];
    float* out = (float*)d_out;

    unsigned short* HWp = (unsigned short*)d_ws;   // 25.6 MB bf16, permuted rows
    const size_t hw_bytes = (size_t)N_NODES * OUT_DIM * sizeof(unsigned short);
    int* row_ptr = (int*)((char*)d_ws + hw_bytes);
    size_t wt_off = hw_bytes + (size_t)(N_NODES + 1) * sizeof(int);
    wt_off = (wt_off + 127) & ~(size_t)127;
    unsigned short* WTx = (unsigned short*)((char*)d_ws + wt_off);

    wt_kernel<<<dim3((IN_DIM * OUT_DIM) / 256), dim3(256), 0, stream>>>(W, WTx);
    rowptr_kernel<<<dim3((N_EDGES + 256) / 256), dim3(256), 0, stream>>>(dst, row_ptr);
    gemm_mfma_kernel<<<dim3((N_NODES + 127) / 128), dim3(256), 0, stream>>>(H, WTx, HWp);
    spmm_v4_kernel<<<dim3((N_NODES + 3) / 4), dim3(256), 0, stream>>>(
        (const uint4*)HWp, vals, src, row_ptr, bias, out);
}